// Round 1
// baseline (713.982 us; speedup 1.0000x reference)
//
#include <hip/hip_runtime.h>

// Problem constants (from reference): N_ATOMS=2e6, D_FEAT=64, OUT_DIM=1,
// N_SPECIES=8, N_STRUCTURES=20000, structural_indices SORTED ascending.

#define DF      64
#define NSPEC   8
#define BLOCK   256
#define CHUNK   2048     // atoms per block
#define NBINS   1024     // LDS segment bins per block (chunk spans ~20 structs typ.)

__global__ void zero_out_kernel(float* __restrict__ out, int n) {
    int i = blockIdx.x * blockDim.x + threadIdx.x;
    if (i < n) out[i] = 0.0f;
}

__global__ __launch_bounds__(BLOCK, 4)
void atoms_segsum_kernel(const float* __restrict__ X,
                         const float* __restrict__ W,        // [NSPEC][DF]
                         const int*   __restrict__ species,  // [N]
                         const int*   __restrict__ sidx,     // [N] sorted
                         float*       __restrict__ out,      // [n_structures]
                         int n_atoms)
{
    __shared__ float w_lds[NSPEC * DF];   // 2 KB
    __shared__ float bins[NBINS];         // 4 KB

    const int t = threadIdx.x;

    // Stage W (tiny) and zero the bins.
    for (int i = t; i < NSPEC * DF; i += BLOCK) w_lds[i] = W[i];
    for (int i = t; i < NBINS; i += BLOCK)      bins[i] = 0.0f;

    const long long a0 = (long long)blockIdx.x * CHUNK;
    const int s_first = sidx[a0];   // sorted => all s in chunk >= s_first

    __syncthreads();

    const int group  = t >> 4;          // 0..15 : which atom of the 16/iter
    const int lane16 = t & 15;          // 0..15 : which feature quad
    const int fl     = lane16 << 2;     // feature offset 0,4,...,60

    #pragma unroll 4
    for (int it = 0; it < CHUNK; it += 16) {
        const long long a = a0 + it + group;
        if (a < n_atoms) {
            const int s = species[a];
            // Coalesced: wave reads contiguous 1 KB (4 atoms x 256 B).
            const float4 x = *(const float4*)(X + a * DF + fl);
            const float* wp = w_lds + s * DF + fl;
            float v = x.x * wp[0] + x.y * wp[1] + x.z * wp[2] + x.w * wp[3];
            // Reduce across the 16 lanes sharing this atom (16-aligned groups,
            // xor masks 1..8 stay inside the group on wave64).
            v += __shfl_xor(v, 1);
            v += __shfl_xor(v, 2);
            v += __shfl_xor(v, 4);
            v += __shfl_xor(v, 8);
            if (lane16 == 0) {
                const int si  = sidx[a];
                const int rel = si - s_first;
                if (rel < NBINS) atomicAdd(&bins[rel], v);   // LDS atomic (fast path)
                else             atomicAdd(&out[si], v);     // pathological fallback
            }
        }
    }

    __syncthreads();

    // Flush non-zero bins: ~chunk/100 global atomics per block.
    for (int i = t; i < NBINS; i += BLOCK) {
        const float v = bins[i];
        if (v != 0.0f) atomicAdd(&out[s_first + i], v);
    }
}

extern "C" void kernel_launch(void* const* d_in, const int* in_sizes, int n_in,
                              void* d_out, int out_size, void* d_ws, size_t ws_size,
                              hipStream_t stream) {
    const float* X       = (const float*)d_in[0];   // [N, 64]
    const float* W       = (const float*)d_in[1];   // [8, 64, 1]
    const int*   species = (const int*)d_in[2];     // [N]
    const int*   sidx    = (const int*)d_in[3];     // [N] sorted
    float*       out     = (float*)d_out;           // [n_structures]

    const int n_atoms = in_sizes[0] / DF;

    // d_out is poisoned before every timed replay -> zero it first.
    {
        int blocks = (out_size + BLOCK - 1) / BLOCK;
        zero_out_kernel<<<blocks, BLOCK, 0, stream>>>(out, out_size);
    }

    const int nblocks = (int)((n_atoms + CHUNK - 1) / CHUNK);
    atoms_segsum_kernel<<<nblocks, BLOCK, 0, stream>>>(X, W, species, sidx,
                                                       out, n_atoms);
}